// Round 13
// baseline (258.722 us; speedup 1.0000x reference)
//
#include <hip/hip_runtime.h>

#define NN 50000
#define NE 600000
#define DD 128
#define RR 8
#define NBASIS 4
#define NR (NN * RR)
#define KTOT 640      // 4*128 (z bases) + 128 (self feat)
#define KZ 512        // z cols (basis part, kept in LDS)
#define MPAD 50048
#define KMASK 0x0FFFFFFF
#define NPB 32        // nodes per block (fused)

typedef float f32x4 __attribute__((ext_vector_type(4)));
typedef float f32x2 __attribute__((ext_vector_type(2)));
typedef short bf16x8 __attribute__((ext_vector_type(8)));
typedef unsigned int u32x4 __attribute__((ext_vector_type(4)));

static __device__ __forceinline__ unsigned short f2b(float f) {
  union { float f; unsigned u; } c; c.f = f;
  unsigned u = c.u + 0x7fffu + ((c.u >> 16) & 1u);  // RNE
  return (unsigned short)(u >> 16);
}
static __device__ __forceinline__ unsigned pack2(float lo, float hi) {
  return (unsigned)f2b(lo) | ((unsigned)f2b(hi) << 16);
}
static __device__ __forceinline__ float b2f_lo(unsigned v) {
  union { unsigned u; float f; } c; c.u = v << 16; return c.f;
}
static __device__ __forceinline__ float b2f_hi(unsigned v) {
  union { unsigned u; float f; } c; c.u = v & 0xffff0000u; return c.f;
}
static __device__ __forceinline__ f32x2 sp2(float s) {
  f32x2 r; r.x = s; r.y = s; return r;
}

// packed-FMA edge accumulate
static __device__ __forceinline__ void fma_bf(f32x2* A0, f32x2* A1, f32x2* A2,
                                              f32x2* A3, u32x4 v, float4 c) {
  f32x2 e0, e1, e2, e3;
  e0.x = b2f_lo(v.x); e0.y = b2f_hi(v.x);
  e1.x = b2f_lo(v.y); e1.y = b2f_hi(v.y);
  e2.x = b2f_lo(v.z); e2.y = b2f_hi(v.z);
  e3.x = b2f_lo(v.w); e3.y = b2f_hi(v.w);
  f32x2 cx = sp2(c.x), cy = sp2(c.y), cz = sp2(c.z), cw = sp2(c.w);
  A0[0] += cx * e0; A0[1] += cx * e1; A0[2] += cx * e2; A0[3] += cx * e3;
  A1[0] += cy * e0; A1[1] += cy * e1; A1[2] += cy * e2; A1[3] += cy * e3;
  A2[0] += cz * e0; A2[1] += cz * e1; A2[2] += cz * e2; A2[3] += cz * e3;
  A3[0] += cw * e0; A3[1] += cw * e1; A3[2] += cw * e2; A3[3] += cw * e3;
}

// cross-group reduce (xor 16/32) + bf16 pack + LDS store of basis g's slice
static __device__ __forceinline__ void reduce_store_lds(
    const f32x2* A0, const f32x2* A1, const f32x2* A2, const f32x2* A3,
    int g, int q, unsigned short* zp /* &zA[zr][0] */) {
  float a0[8] = {A0[0].x, A0[0].y, A0[1].x, A0[1].y,
                 A0[2].x, A0[2].y, A0[3].x, A0[3].y};
  float a1[8] = {A1[0].x, A1[0].y, A1[1].x, A1[1].y,
                 A1[2].x, A1[2].y, A1[3].x, A1[3].y};
  float a2[8] = {A2[0].x, A2[0].y, A2[1].x, A2[1].y,
                 A2[2].x, A2[2].y, A2[3].x, A2[3].y};
  float a3[8] = {A3[0].x, A3[0].y, A3[1].x, A3[1].y,
                 A3[2].x, A3[2].y, A3[3].x, A3[3].y};
#pragma unroll
  for (int j = 0; j < 8; ++j) {
    a0[j] += __shfl_xor(a0[j], 16); a0[j] += __shfl_xor(a0[j], 32);
    a1[j] += __shfl_xor(a1[j], 16); a1[j] += __shfl_xor(a1[j], 32);
    a2[j] += __shfl_xor(a2[j], 16); a2[j] += __shfl_xor(a2[j], 32);
    a3[j] += __shfl_xor(a3[j], 16); a3[j] += __shfl_xor(a3[j], 32);
  }
  u32x4 wv;
  if (g == 0) {
    wv.x = pack2(a0[0], a0[1]); wv.y = pack2(a0[2], a0[3]);
    wv.z = pack2(a0[4], a0[5]); wv.w = pack2(a0[6], a0[7]);
  } else if (g == 1) {
    wv.x = pack2(a1[0], a1[1]); wv.y = pack2(a1[2], a1[3]);
    wv.z = pack2(a1[4], a1[5]); wv.w = pack2(a1[6], a1[7]);
  } else if (g == 2) {
    wv.x = pack2(a2[0], a2[1]); wv.y = pack2(a2[2], a2[3]);
    wv.z = pack2(a2[4], a2[5]); wv.w = pack2(a2[6], a2[7]);
  } else {
    wv.x = pack2(a3[0], a3[1]); wv.y = pack2(a3[2], a3[3]);
    wv.z = pack2(a3[4], a3[5]); wv.w = pack2(a3[6], a3[7]);
  }
  *(u32x4*)(zp + g * 128 + q * 8) = wv;
}

// ---------------------------------------------------------------------------
// prep: bf16-convert x, build BT1/BT2, count edges per (dst,etype).
#define PREP_XB 12500
#define PREP_BT 320
#define PREP_CNT 2344
#define PREP_TOTAL (PREP_XB + 2 * PREP_BT + PREP_CNT)

__global__ __launch_bounds__(256) void prep_kernel(
    const float* __restrict__ x, const float* __restrict__ basis1,
    const float* __restrict__ root1, const float* __restrict__ basis2,
    const float* __restrict__ root2, const int* __restrict__ dst,
    const int* __restrict__ et, unsigned* __restrict__ xb,
    unsigned short* __restrict__ BT1, unsigned short* __restrict__ BT2,
    int* __restrict__ cnt) {
  int bid = blockIdx.x;
  int t = threadIdx.x;
  if (bid < PREP_XB) {
    int i = bid * 256 + t;
    float2 v = ((const float2*)x)[i];
    xb[i] = pack2(v.x, v.y);
  } else if (bid < PREP_XB + PREP_BT) {
    int idx = (bid - PREP_XB) * 256 + t;
    int c = idx / KTOT, k = idx - c * KTOT;
    float v = (k < 512) ? basis1[(size_t)((k >> 7) * DD + (k & 127)) * DD + c]
                        : root1[(size_t)(k - 512) * DD + c];
    BT1[idx] = f2b(v);
  } else if (bid < PREP_XB + 2 * PREP_BT) {
    int idx = (bid - PREP_XB - PREP_BT) * 256 + t;
    int c = idx / KTOT, k = idx - c * KTOT;
    float v = (k < 512) ? basis2[(size_t)((k >> 7) * DD + (k & 127)) * DD + c]
                        : root2[(size_t)(k - 512) * DD + c];
    BT2[idx] = f2b(v);
  } else {
    int e = (bid - PREP_XB - 2 * PREP_BT) * 256 + t;
    if (e < NE) atomicAdd(&cnt[dst[e] * RR + et[e]], 1);
  }
}

// ---------------------------------------------------------------------------
__global__ __launch_bounds__(256) void offs_kernel(
    const int* __restrict__ cnt, int2* __restrict__ od,
    int* __restrict__ curs, int* __restrict__ gcur) {
  __shared__ int s[256];
  __shared__ int base;
  int t = threadIdx.x;
  int i = blockIdx.x * 256 + t;
  int v = 0;
  if (i < NN) {
    const int4* c4 = (const int4*)cnt;
    int4 a = c4[i * 2];
    int4 b = c4[i * 2 + 1];
    v = a.x + a.y + a.z + a.w + b.x + b.y + b.z + b.w;
  }
  s[t] = v;
  __syncthreads();
  for (int off = 1; off < 256; off <<= 1) {
    int add = (t >= off) ? s[t - off] : 0;
    __syncthreads();
    s[t] += add;
    __syncthreads();
  }
  if (t == 255) base = atomicAdd(gcur, s[255]);
  __syncthreads();
  if (i < NN) {
    int o = base + s[t] - v;
    od[i] = make_int2(o, v);
    curs[i] = o;
  }
}

// ---------------------------------------------------------------------------
__global__ __launch_bounds__(256) void sort_kernel(
    const int* __restrict__ src, const int* __restrict__ dst,
    const int* __restrict__ et, int* __restrict__ curs,
    int* __restrict__ skey) {
  int e = blockIdx.x * 256 + threadIdx.x;
  if (e >= NE) return;
  int p = atomicAdd(&curs[dst[e]], 1);
  skey[p] = src[e] | (et[e] << 28);
}

// ---------------------------------------------------------------------------
// Fused layer: phase A aggregates 32 nodes into LDS z (8 nodes/wave via 4
// rounds of the 2-node cross-pipelined gather), phase B does the 32x128
// MFMA GEMM over K=640 with z resident in LDS (padded: conflict-free),
// Bs/fS staged per K-step.  2 blocks/CU -> phase A of one block overlaps
// phase B of the other.
template <int OUT_BF16>
__global__ __launch_bounds__(256) void rgcn_fused(
    const u32x4* __restrict__ featb4,        // [MPAD][16] bf16 rows
    const unsigned short* __restrict__ feat, // same buffer as ushort
    const int* __restrict__ skey, const int* __restrict__ cnt,
    const float* __restrict__ comp, const int2* __restrict__ od,
    const unsigned short* __restrict__ BT,   // [128][640] bf16
    const float* __restrict__ bias, void* __restrict__ Cout) {
  __shared__ unsigned short zA[NPB][520];  // 33.3 KB, +8 pad (2-way = free)
  __shared__ unsigned short Bs[128][72];   // 18.4 KB
  __shared__ unsigned short fS[NPB][72];   //  4.6 KB
  __shared__ float ccl[8][RR * NBASIS];    //  1 KB

  int tid = threadIdx.x;
  int w = tid >> 6;
  int lane = tid & 63;
  int g = lane >> 4;
  int q = lane & 15;
  int nb = blockIdx.x * NPB;

  // ================= phase A: aggregate 8 nodes per wave =================
  for (int rr = 0; rr < 4; ++rr) {
    int nA = nb + w * 8 + rr * 2;
    int nB = nA + 1;
    int ncA = min(nA, NN - 1);
    int ncB = min(nB, NN - 1);
    {
      int which = lane >> 5;
      int idx = lane & 31;
      int nodec = which ? ncB : ncA;
      int c = cnt[nodec * RR + (idx >> 2)];
      ccl[w * 2 + which][idx] = comp[idx] * (1.0f / (float)max(c, 1));
    }
    int2 odA = od[ncA];
    int2 odB = od[ncB];
    int begA = odA.x, dgA = (nA < NN) ? odA.y : 0;
    int begB = odB.x, dgB = (nB < NN) ? odB.y : 0;
    int lastA = min(begA + max(dgA, 1) - 1, NE - 1);
    int lastB = min(begB + max(dgB, 1) - 1, NE - 1);

    // round-0 loads, node A
    int pA0 = min(begA + g, lastA);
    int pA1 = min(begA + g + 4, lastA);
    int pA2 = min(begA + g + 8, lastA);
    int kA0 = skey[pA0], kA1 = skey[pA1], kA2 = skey[pA2];
    u32x4 vA0 = featb4[(size_t)(kA0 & KMASK) * 16 + q];
    u32x4 vA1 = featb4[(size_t)(kA1 & KMASK) * 16 + q];
    u32x4 vA2 = featb4[(size_t)(kA2 & KMASK) * 16 + q];

    // round-0 loads, node B (independent; overlaps A's consumption)
    int pB0 = min(begB + g, lastB);
    int pB1 = min(begB + g + 4, lastB);
    int pB2 = min(begB + g + 8, lastB);
    int kB0 = skey[pB0], kB1 = skey[pB1], kB2 = skey[pB2];
    u32x4 vB0 = featb4[(size_t)(kB0 & KMASK) * 16 + q];
    u32x4 vB1 = featb4[(size_t)(kB1 & KMASK) * 16 + q];
    u32x4 vB2 = featb4[(size_t)(kB2 & KMASK) * 16 + q];

    f32x2 A0[4] = {}, A1[4] = {}, A2[4] = {}, A3[4] = {};

    // consume node A
    {
      const float4* cc4 = (const float4*)ccl[w * 2];
      float4 c0 = cc4[((unsigned)kA0) >> 28];
      float4 c1 = cc4[((unsigned)kA1) >> 28];
      float4 c2 = cc4[((unsigned)kA2) >> 28];
      float s0 = (g < dgA) ? 1.f : 0.f;
      float s1 = (g + 4 < dgA) ? 1.f : 0.f;
      float s2 = (g + 8 < dgA) ? 1.f : 0.f;
      c0.x *= s0; c0.y *= s0; c0.z *= s0; c0.w *= s0;
      c1.x *= s1; c1.y *= s1; c1.z *= s1; c1.w *= s1;
      c2.x *= s2; c2.y *= s2; c2.z *= s2; c2.w *= s2;
      fma_bf(A0, A1, A2, A3, vA0, c0);
      fma_bf(A0, A1, A2, A3, vA1, c1);
      fma_bf(A0, A1, A2, A3, vA2, c2);
      for (int i = g + 12; i < dgA; i += 12) {
        int p0 = begA + i;
        int p1 = min(p0 + 4, lastA);
        int p2 = min(p0 + 8, lastA);
        int k0 = skey[p0], k1 = skey[p1], k2 = skey[p2];
        u32x4 v0 = featb4[(size_t)(k0 & KMASK) * 16 + q];
        u32x4 v1 = featb4[(size_t)(k1 & KMASK) * 16 + q];
        u32x4 v2 = featb4[(size_t)(k2 & KMASK) * 16 + q];
        float4 c0t = cc4[((unsigned)k0) >> 28];
        float4 c1t = cc4[((unsigned)k1) >> 28];
        float4 c2t = cc4[((unsigned)k2) >> 28];
        float t1 = (i + 4 < dgA) ? 1.f : 0.f;
        float t2 = (i + 8 < dgA) ? 1.f : 0.f;
        c1t.x *= t1; c1t.y *= t1; c1t.z *= t1; c1t.w *= t1;
        c2t.x *= t2; c2t.y *= t2; c2t.z *= t2; c2t.w *= t2;
        fma_bf(A0, A1, A2, A3, v0, c0t);
        fma_bf(A0, A1, A2, A3, v1, c1t);
        fma_bf(A0, A1, A2, A3, v2, c2t);
      }
      reduce_store_lds(A0, A1, A2, A3, g, q, &zA[w * 8 + rr * 2][0]);
    }

    // consume node B
    {
#pragma unroll
      for (int j = 0; j < 4; ++j) {
        A0[j] = sp2(0.f); A1[j] = sp2(0.f); A2[j] = sp2(0.f); A3[j] = sp2(0.f);
      }
      const float4* cc4 = (const float4*)ccl[w * 2 + 1];
      float4 c0 = cc4[((unsigned)kB0) >> 28];
      float4 c1 = cc4[((unsigned)kB1) >> 28];
      float4 c2 = cc4[((unsigned)kB2) >> 28];
      float s0 = (g < dgB) ? 1.f : 0.f;
      float s1 = (g + 4 < dgB) ? 1.f : 0.f;
      float s2 = (g + 8 < dgB) ? 1.f : 0.f;
      c0.x *= s0; c0.y *= s0; c0.z *= s0; c0.w *= s0;
      c1.x *= s1; c1.y *= s1; c1.z *= s1; c1.w *= s1;
      c2.x *= s2; c2.y *= s2; c2.z *= s2; c2.w *= s2;
      fma_bf(A0, A1, A2, A3, vB0, c0);
      fma_bf(A0, A1, A2, A3, vB1, c1);
      fma_bf(A0, A1, A2, A3, vB2, c2);
      for (int i = g + 12; i < dgB; i += 12) {
        int p0 = begB + i;
        int p1 = min(p0 + 4, lastB);
        int p2 = min(p0 + 8, lastB);
        int k0 = skey[p0], k1 = skey[p1], k2 = skey[p2];
        u32x4 v0 = featb4[(size_t)(k0 & KMASK) * 16 + q];
        u32x4 v1 = featb4[(size_t)(k1 & KMASK) * 16 + q];
        u32x4 v2 = featb4[(size_t)(k2 & KMASK) * 16 + q];
        float4 c0t = cc4[((unsigned)k0) >> 28];
        float4 c1t = cc4[((unsigned)k1) >> 28];
        float4 c2t = cc4[((unsigned)k2) >> 28];
        float t1 = (i + 4 < dgB) ? 1.f : 0.f;
        float t2 = (i + 8 < dgB) ? 1.f : 0.f;
        c1t.x *= t1; c1t.y *= t1; c1t.z *= t1; c1t.w *= t1;
        c2t.x *= t2; c2t.y *= t2; c2t.z *= t2; c2t.w *= t2;
        fma_bf(A0, A1, A2, A3, v0, c0t);
        fma_bf(A0, A1, A2, A3, v1, c1t);
        fma_bf(A0, A1, A2, A3, v2, c2t);
      }
      reduce_store_lds(A0, A1, A2, A3, g, q, &zA[w * 8 + rr * 2 + 1][0]);
    }
  }

  // ================= phase B: 32x128 GEMM over K=640 =================
  int wc = w * 32;
  f32x4 acc[2][2] = {};

  for (int kt = 0; kt < KTOT; kt += 64) {
    // stage Bs [128][64] (+pad): 1024 16B chunks, 4/thread
#pragma unroll
    for (int i = 0; i < 4; ++i) {
      int off = i * 256 + tid;
      int r = off >> 3;
      int ke = (off & 7) << 3;
      *(u32x4*)&Bs[r][ke] = *(const u32x4*)(BT + (size_t)r * KTOT + kt + ke);
    }
    if (kt >= KZ) {
      // stage fS [32][64] (+pad): 256 chunks, 1/thread
      int r = tid >> 3;
      int ke = (tid & 7) << 3;
      *(u32x4*)&fS[r][ke] =
          *(const u32x4*)(feat + (size_t)(nb + r) * DD + (kt - KZ) + ke);
    }
    __syncthreads();

#pragma unroll
    for (int kk = 0; kk < 2; ++kk) {
      int ko = kk * 32 + ((lane >> 4) << 3);
      bf16x8 a[2], b[2];
#pragma unroll
      for (int m = 0; m < 2; ++m)
        a[m] = (kt < KZ)
                   ? *(const bf16x8*)&zA[m * 16 + (lane & 15)][kt + ko]
                   : *(const bf16x8*)&fS[m * 16 + (lane & 15)][ko];
#pragma unroll
      for (int n = 0; n < 2; ++n)
        b[n] = *(const bf16x8*)&Bs[wc + n * 16 + (lane & 15)][ko];
#pragma unroll
      for (int m = 0; m < 2; ++m)
#pragma unroll
        for (int n = 0; n < 2; ++n)
          acc[m][n] = __builtin_amdgcn_mfma_f32_16x16x32_bf16(
              a[m], b[n], acc[m][n], 0, 0, 0);
    }
    __syncthreads();
  }

#pragma unroll
  for (int n = 0; n < 2; ++n) {
    int col = wc + n * 16 + (lane & 15);
    float bb = bias[col];
#pragma unroll
    for (int m = 0; m < 2; ++m) {
      f32x4 v = acc[m][n];
#pragma unroll
      for (int j = 0; j < 4; ++j) {
        int row = nb + m * 16 + ((lane >> 4) << 2) + j;
        if (row < NN) {
          float o = v[j] + bb;
          if (OUT_BF16) {
            o = fmaxf(o, 0.f);
            ((unsigned short*)Cout)[(size_t)row * DD + col] = f2b(o);
          } else {
            ((float*)Cout)[(size_t)row * DD + col] = o;
          }
        }
      }
    }
  }
}

// ---------------------------------------------------------------------------
extern "C" void kernel_launch(void* const* d_in, const int* in_sizes, int n_in,
                              void* d_out, int out_size, void* d_ws,
                              size_t ws_size, hipStream_t stream) {
  const float* x      = (const float*)d_in[0];
  const int*   eidx   = (const int*)d_in[1];
  const int*   etype  = (const int*)d_in[2];
  const float* basis1 = (const float*)d_in[3];
  const float* comp1  = (const float*)d_in[4];
  const float* root1  = (const float*)d_in[5];
  const float* bias1  = (const float*)d_in[6];
  const float* basis2 = (const float*)d_in[7];
  const float* comp2  = (const float*)d_in[8];
  const float* root2  = (const float*)d_in[9];
  const float* bias2  = (const float*)d_in[10];
  float* out = (float*)d_out;

  const int* src = eidx;
  const int* dst = eidx + NE;

  // workspace layout (no Ab anymore)
  unsigned short* xb  = (unsigned short*)d_ws;         // [MPAD][128] bf16
  unsigned short* hb  = xb + (size_t)MPAD * DD;        // [MPAD][128] bf16
  unsigned short* BT1 = hb + (size_t)MPAD * DD;        // [128][640] bf16
  unsigned short* BT2 = BT1 + (size_t)DD * KTOT;
  int*  skey = (int*)(BT2 + (size_t)DD * KTOT);        // [NE]
  int*  cnt  = skey + NE;                              // [NR]
  int*  gcur = cnt + NR;                               // [4]
  int2* od   = (int2*)(gcur + 4);                      // [NN]
  int*  curs = (int*)(od + NN);                        // [NN]

  const int NB = (NN + 255) / 256;  // 196
  const int EB = (NE + 255) / 256;  // 2344

  hipMemsetAsync(cnt, 0, (size_t)(NR + 4) * sizeof(int), stream);
  prep_kernel<<<PREP_TOTAL, 256, 0, stream>>>(
      x, basis1, root1, basis2, root2, dst, etype, (unsigned*)xb, BT1, BT2,
      cnt);
  offs_kernel<<<NB, 256, 0, stream>>>(cnt, od, curs, gcur);
  sort_kernel<<<EB, 256, 0, stream>>>(src, dst, etype, curs, skey);

  int fused_blocks = (NN + NPB - 1) / NPB;  // 1563

  // ---- layer 1 (x -> h, relu, bf16) ----
  rgcn_fused<1><<<fused_blocks, 256, 0, stream>>>(
      (const u32x4*)xb, xb, skey, cnt, comp1, od, BT1, bias1, hb);
  // ---- layer 2 (h -> out, f32) ----
  rgcn_fused<0><<<fused_blocks, 256, 0, stream>>>(
      (const u32x4*)hb, hb, skey, cnt, comp2, od, BT2, bias2, out);
}

// Round 14
// 232.343 us; speedup vs baseline: 1.1135x; 1.1135x over previous
//
#include <hip/hip_runtime.h>

#define NN 50000
#define NE 600000
#define DD 128
#define RR 8
#define NBASIS 4
#define NR (NN * RR)
#define KTOT 640      // 4*128 (z bases) + 128 (self feat, read from table)
#define KZ 512        // stored A-matrix cols (basis part only)
#define MPAD 50048    // 391 * 128
#define KMASK 0x0FFFFFFF

typedef float f32x4 __attribute__((ext_vector_type(4)));
typedef short bf16x8 __attribute__((ext_vector_type(8)));
typedef unsigned int u32x4 __attribute__((ext_vector_type(4)));

static __device__ __forceinline__ unsigned short f2b(float f) {
  union { float f; unsigned u; } c; c.f = f;
  unsigned u = c.u + 0x7fffu + ((c.u >> 16) & 1u);  // RNE
  return (unsigned short)(u >> 16);
}
static __device__ __forceinline__ unsigned pack2(float lo, float hi) {
  return (unsigned)f2b(lo) | ((unsigned)f2b(hi) << 16);
}
static __device__ __forceinline__ float b2f_lo(unsigned v) {
  union { unsigned u; float f; } c; c.u = v << 16; return c.f;
}
static __device__ __forceinline__ float b2f_hi(unsigned v) {
  union { unsigned u; float f; } c; c.u = v & 0xffff0000u; return c.f;
}

static __device__ __forceinline__ void fma8(float* a0, float* a1, float* a2,
                                            float* a3, u32x4 v, float4 c) {
  float e[8];
  e[0] = b2f_lo(v.x); e[1] = b2f_hi(v.x);
  e[2] = b2f_lo(v.y); e[3] = b2f_hi(v.y);
  e[4] = b2f_lo(v.z); e[5] = b2f_hi(v.z);
  e[6] = b2f_lo(v.w); e[7] = b2f_hi(v.w);
#pragma unroll
  for (int j = 0; j < 8; ++j) {
    a0[j] += c.x * e[j];
    a1[j] += c.y * e[j];
    a2[j] += c.z * e[j];
    a3[j] += c.w * e[j];
  }
}

// ---------------------------------------------------------------------------
// prep: bf16-convert x, build BT1/BT2, count edges per (dst,etype).
#define PREP_XB 12500                    // NN*DD/2 / 256
#define PREP_BT 320                      // DD*KTOT / 256
#define PREP_CNT 2344                    // ceil(NE/256)
#define PREP_TOTAL (PREP_XB + 2 * PREP_BT + PREP_CNT)

__global__ __launch_bounds__(256) void prep_kernel(
    const float* __restrict__ x, const float* __restrict__ basis1,
    const float* __restrict__ root1, const float* __restrict__ basis2,
    const float* __restrict__ root2, const int* __restrict__ dst,
    const int* __restrict__ et, unsigned* __restrict__ xb,
    unsigned short* __restrict__ BT1, unsigned short* __restrict__ BT2,
    int* __restrict__ cnt) {
  int bid = blockIdx.x;
  int t = threadIdx.x;
  if (bid < PREP_XB) {
    int i = bid * 256 + t;  // exact: NN*DD/2 = 12500*256
    float2 v = ((const float2*)x)[i];
    xb[i] = pack2(v.x, v.y);
  } else if (bid < PREP_XB + PREP_BT) {
    int idx = (bid - PREP_XB) * 256 + t;  // exact: DD*KTOT = 320*256
    int c = idx / KTOT, k = idx - c * KTOT;
    float v = (k < 512) ? basis1[(size_t)((k >> 7) * DD + (k & 127)) * DD + c]
                        : root1[(size_t)(k - 512) * DD + c];
    BT1[idx] = f2b(v);
  } else if (bid < PREP_XB + 2 * PREP_BT) {
    int idx = (bid - PREP_XB - PREP_BT) * 256 + t;
    int c = idx / KTOT, k = idx - c * KTOT;
    float v = (k < 512) ? basis2[(size_t)((k >> 7) * DD + (k & 127)) * DD + c]
                        : root2[(size_t)(k - 512) * DD + c];
    BT2[idx] = f2b(v);
  } else {
    int e = (bid - PREP_XB - 2 * PREP_BT) * 256 + t;
    if (e < NE) atomicAdd(&cnt[dst[e] * RR + et[e]], 1);
  }
}

// ---------------------------------------------------------------------------
// offs: deg from cnt row-sum, block-scan + one atomic for global base.
__global__ __launch_bounds__(256) void offs_kernel(
    const int* __restrict__ cnt, int2* __restrict__ od,
    int* __restrict__ curs, int* __restrict__ gcur) {
  __shared__ int s[256];
  __shared__ int base;
  int t = threadIdx.x;
  int i = blockIdx.x * 256 + t;
  int v = 0;
  if (i < NN) {
    const int4* c4 = (const int4*)cnt;
    int4 a = c4[i * 2];
    int4 b = c4[i * 2 + 1];
    v = a.x + a.y + a.z + a.w + b.x + b.y + b.z + b.w;
  }
  s[t] = v;
  __syncthreads();
  for (int off = 1; off < 256; off <<= 1) {
    int add = (t >= off) ? s[t - off] : 0;
    __syncthreads();
    s[t] += add;
    __syncthreads();
  }
  if (t == 255) base = atomicAdd(gcur, s[255]);
  __syncthreads();
  if (i < NN) {
    int o = base + s[t] - v;
    od[i] = make_int2(o, v);
    curs[i] = o;
  }
}

// ---------------------------------------------------------------------------
__global__ __launch_bounds__(256) void sort_kernel(
    const int* __restrict__ src, const int* __restrict__ dst,
    const int* __restrict__ et, int* __restrict__ curs,
    int* __restrict__ skey) {
  int e = blockIdx.x * 256 + threadIdx.x;
  if (e >= NE) return;
  int p = atomicAdd(&curs[dst[e]], 1);
  skey[p] = src[e] | (et[e] << 28);
}

// ---------------------------------------------------------------------------
// TWO nodes per wave, cross-node software pipeline: issue node-A's round-0
// key+feature loads, then node-B's (independent, overlap under vmcnt), then
// consume A (FMA + tail + reduce + NT-store) while B's loads fly, then B.
// Per node: 4x16-lane edge groups x 3 slots = 12 gathers (~= mean degree).
// Coeffs comp[t][b]/cnt[node,t] staged in LDS per node.
__global__ __launch_bounds__(256) void agg_kernel(
    const u32x4* __restrict__ featb4,   // [MPAD][16] bf16 rows as u32x4
    const int* __restrict__ skey, const int* __restrict__ cnt,
    const float* __restrict__ comp, const int2* __restrict__ od,
    u32x4* __restrict__ Ab4) {          // [MPAD][64] (512 bf16 cols)
  __shared__ float ccl[8][RR * NBASIS];
  int tid = threadIdx.x;
  int w = tid >> 6;
  int lane = tid & 63;
  int nA = blockIdx.x * 8 + w * 2;      // 6250 * 8 == NN exactly
  int nB = nA + 1;
  int g = lane >> 4;
  int q = lane & 15;

  // coeffs for both nodes in one shot: lanes 0..31 -> A, 32..63 -> B
  {
    int which = lane >> 5;
    int idx = lane & 31;
    int node = nA + which;
    int c = cnt[node * RR + (idx >> 2)];
    ccl[w * 2 + which][idx] = comp[idx] * (1.0f / (float)max(c, 1));
  }
  __syncthreads();

  int2 odA = od[nA];
  int2 odB = od[nB];
  int begA = odA.x, dgA = odA.y;
  int begB = odB.x, dgB = odB.y;
  int lastA = min(begA + max(dgA, 1) - 1, NE - 1);
  int lastB = min(begB + max(dgB, 1) - 1, NE - 1);

  // ---- round-0 loads, node A ----
  int pA0 = min(begA + g, lastA);
  int pA1 = min(begA + g + 4, lastA);
  int pA2 = min(begA + g + 8, lastA);
  int kA0 = skey[pA0], kA1 = skey[pA1], kA2 = skey[pA2];
  u32x4 vA0 = featb4[(size_t)(kA0 & KMASK) * 16 + q];
  u32x4 vA1 = featb4[(size_t)(kA1 & KMASK) * 16 + q];
  u32x4 vA2 = featb4[(size_t)(kA2 & KMASK) * 16 + q];

  // ---- round-0 loads, node B (independent; overlaps A's consumption) ----
  int pB0 = min(begB + g, lastB);
  int pB1 = min(begB + g + 4, lastB);
  int pB2 = min(begB + g + 8, lastB);
  int kB0 = skey[pB0], kB1 = skey[pB1], kB2 = skey[pB2];
  u32x4 vB0 = featb4[(size_t)(kB0 & KMASK) * 16 + q];
  u32x4 vB1 = featb4[(size_t)(kB1 & KMASK) * 16 + q];
  u32x4 vB2 = featb4[(size_t)(kB2 & KMASK) * 16 + q];

  float a0[8] = {}, a1[8] = {}, a2[8] = {}, a3[8] = {};

  // ================= consume node A =================
  {
    const float4* cc4 = (const float4*)ccl[w * 2];
    float4 c0 = cc4[((unsigned)kA0) >> 28];
    float4 c1 = cc4[((unsigned)kA1) >> 28];
    float4 c2 = cc4[((unsigned)kA2) >> 28];
    float s0 = (g < dgA) ? 1.f : 0.f;
    float s1 = (g + 4 < dgA) ? 1.f : 0.f;
    float s2 = (g + 8 < dgA) ? 1.f : 0.f;
    c0.x *= s0; c0.y *= s0; c0.z *= s0; c0.w *= s0;
    c1.x *= s1; c1.y *= s1; c1.z *= s1; c1.w *= s1;
    c2.x *= s2; c2.y *= s2; c2.z *= s2; c2.w *= s2;
    fma8(a0, a1, a2, a3, vA0, c0);
    fma8(a0, a1, a2, a3, vA1, c1);
    fma8(a0, a1, a2, a3, vA2, c2);

    for (int i = g + 12; i < dgA; i += 12) {
      int p0 = begA + i;
      int p1 = min(p0 + 4, lastA);
      int p2 = min(p0 + 8, lastA);
      int k0 = skey[p0], k1 = skey[p1], k2 = skey[p2];
      u32x4 v0 = featb4[(size_t)(k0 & KMASK) * 16 + q];
      u32x4 v1 = featb4[(size_t)(k1 & KMASK) * 16 + q];
      u32x4 v2 = featb4[(size_t)(k2 & KMASK) * 16 + q];
      float4 c0t = cc4[((unsigned)k0) >> 28];
      float4 c1t = cc4[((unsigned)k1) >> 28];
      float4 c2t = cc4[((unsigned)k2) >> 28];
      float t1 = (i + 4 < dgA) ? 1.f : 0.f;
      float t2 = (i + 8 < dgA) ? 1.f : 0.f;
      c1t.x *= t1; c1t.y *= t1; c1t.z *= t1; c1t.w *= t1;
      c2t.x *= t2; c2t.y *= t2; c2t.z *= t2; c2t.w *= t2;
      fma8(a0, a1, a2, a3, v0, c0t);
      fma8(a0, a1, a2, a3, v1, c1t);
      fma8(a0, a1, a2, a3, v2, c2t);
    }

#pragma unroll
    for (int j = 0; j < 8; ++j) {
      a0[j] += __shfl_xor(a0[j], 16); a0[j] += __shfl_xor(a0[j], 32);
      a1[j] += __shfl_xor(a1[j], 16); a1[j] += __shfl_xor(a1[j], 32);
      a2[j] += __shfl_xor(a2[j], 16); a2[j] += __shfl_xor(a2[j], 32);
      a3[j] += __shfl_xor(a3[j], 16); a3[j] += __shfl_xor(a3[j], 32);
    }
    u32x4 wv;
    if (g == 0) {
      wv.x = pack2(a0[0], a0[1]); wv.y = pack2(a0[2], a0[3]);
      wv.z = pack2(a0[4], a0[5]); wv.w = pack2(a0[6], a0[7]);
    } else if (g == 1) {
      wv.x = pack2(a1[0], a1[1]); wv.y = pack2(a1[2], a1[3]);
      wv.z = pack2(a1[4], a1[5]); wv.w = pack2(a1[6], a1[7]);
    } else if (g == 2) {
      wv.x = pack2(a2[0], a2[1]); wv.y = pack2(a2[2], a2[3]);
      wv.z = pack2(a2[4], a2[5]); wv.w = pack2(a2[6], a2[7]);
    } else {
      wv.x = pack2(a3[0], a3[1]); wv.y = pack2(a3[2], a3[3]);
      wv.z = pack2(a3[4], a3[5]); wv.w = pack2(a3[6], a3[7]);
    }
    __builtin_nontemporal_store(wv, Ab4 + (size_t)nA * 64 + g * 16 + q);
  }

  // ================= consume node B =================
  {
#pragma unroll
    for (int j = 0; j < 8; ++j) { a0[j] = 0.f; a1[j] = 0.f; a2[j] = 0.f; a3[j] = 0.f; }
    const float4* cc4 = (const float4*)ccl[w * 2 + 1];
    float4 c0 = cc4[((unsigned)kB0) >> 28];
    float4 c1 = cc4[((unsigned)kB1) >> 28];
    float4 c2 = cc4[((unsigned)kB2) >> 28];
    float s0 = (g < dgB) ? 1.f : 0.f;
    float s1 = (g + 4 < dgB) ? 1.f : 0.f;
    float s2 = (g + 8 < dgB) ? 1.f : 0.f;
    c0.x *= s0; c0.y *= s0; c0.z *= s0; c0.w *= s0;
    c1.x *= s1; c1.y *= s1; c1.z *= s1; c1.w *= s1;
    c2.x *= s2; c2.y *= s2; c2.z *= s2; c2.w *= s2;
    fma8(a0, a1, a2, a3, vB0, c0);
    fma8(a0, a1, a2, a3, vB1, c1);
    fma8(a0, a1, a2, a3, vB2, c2);

    for (int i = g + 12; i < dgB; i += 12) {
      int p0 = begB + i;
      int p1 = min(p0 + 4, lastB);
      int p2 = min(p0 + 8, lastB);
      int k0 = skey[p0], k1 = skey[p1], k2 = skey[p2];
      u32x4 v0 = featb4[(size_t)(k0 & KMASK) * 16 + q];
      u32x4 v1 = featb4[(size_t)(k1 & KMASK) * 16 + q];
      u32x4 v2 = featb4[(size_t)(k2 & KMASK) * 16 + q];
      float4 c0t = cc4[((unsigned)k0) >> 28];
      float4 c1t = cc4[((unsigned)k1) >> 28];
      float4 c2t = cc4[((unsigned)k2) >> 28];
      float t1 = (i + 4 < dgB) ? 1.f : 0.f;
      float t2 = (i + 8 < dgB) ? 1.f : 0.f;
      c1t.x *= t1; c1t.y *= t1; c1t.z *= t1; c1t.w *= t1;
      c2t.x *= t2; c2t.y *= t2; c2t.z *= t2; c2t.w *= t2;
      fma8(a0, a1, a2, a3, v0, c0t);
      fma8(a0, a1, a2, a3, v1, c1t);
      fma8(a0, a1, a2, a3, v2, c2t);
    }

#pragma unroll
    for (int j = 0; j < 8; ++j) {
      a0[j] += __shfl_xor(a0[j], 16); a0[j] += __shfl_xor(a0[j], 32);
      a1[j] += __shfl_xor(a1[j], 16); a1[j] += __shfl_xor(a1[j], 32);
      a2[j] += __shfl_xor(a2[j], 16); a2[j] += __shfl_xor(a2[j], 32);
      a3[j] += __shfl_xor(a3[j], 16); a3[j] += __shfl_xor(a3[j], 32);
    }
    u32x4 wv;
    if (g == 0) {
      wv.x = pack2(a0[0], a0[1]); wv.y = pack2(a0[2], a0[3]);
      wv.z = pack2(a0[4], a0[5]); wv.w = pack2(a0[6], a0[7]);
    } else if (g == 1) {
      wv.x = pack2(a1[0], a1[1]); wv.y = pack2(a1[2], a1[3]);
      wv.z = pack2(a1[4], a1[5]); wv.w = pack2(a1[6], a1[7]);
    } else if (g == 2) {
      wv.x = pack2(a2[0], a2[1]); wv.y = pack2(a2[2], a2[3]);
      wv.z = pack2(a2[4], a2[5]); wv.w = pack2(a2[6], a2[7]);
    } else {
      wv.x = pack2(a3[0], a3[1]); wv.y = pack2(a3[2], a3[3]);
      wv.z = pack2(a3[4], a3[5]); wv.w = pack2(a3[6], a3[7]);
    }
    __builtin_nontemporal_store(wv, Ab4 + (size_t)nB * 64 + g * 16 + q);
  }
}

// ---------------------------------------------------------------------------
// C[M,128] = [Ab | feat][M,640]bf16 @ BT^T + bias.  A cols 0..511 from Ab
// (nontemporal: streamed once), cols 512..639 from the feature table
// (cached).  128x128 tile, BK=64, 4 waves 2x2, mfma_f32_16x16x32_bf16.
template <int OUT_BF16>
__global__ __launch_bounds__(256) void gemm_mfma(
    const unsigned short* __restrict__ Ab,    // [MPAD][512]
    const unsigned short* __restrict__ feat,  // [MPAD][128]
    const unsigned short* __restrict__ BT,    // [128][640]
    const float* __restrict__ bias, void* __restrict__ Cout) {
  __shared__ unsigned short As[128][64];  // [row][k]
  __shared__ unsigned short Bs[128][64];  // [col][k]

  int tid = threadIdx.x;
  int row0 = blockIdx.x * 128;
  int lane = tid & 63;
  int wid = tid >> 6;
  int wr = (wid >> 1) * 64;
  int wc = (wid & 1) * 64;

  f32x4 acc[4][4] = {};

  for (int kt = 0; kt < KTOT; kt += 64) {
#pragma unroll
    for (int i = 0; i < 4; ++i) {
      int off = i * 256 + tid;      // 16B chunk index, 0..1023
      int r = off >> 3;             // row (As) / col (Bs)
      int ke = (off & 7) << 3;      // bf16 element offset in [0,64)
      u32x4 av;
      if (kt < KZ)
        av = __builtin_nontemporal_load(
            (const u32x4*)(Ab + (size_t)(row0 + r) * KZ + kt + ke));
      else
        av = *(const u32x4*)(feat + (size_t)(row0 + r) * DD + (kt - KZ) + ke);
      *(u32x4*)((unsigned short*)As + (size_t)off * 8) = av;
      *(u32x4*)((unsigned short*)Bs + (size_t)off * 8) =
          *(const u32x4*)(BT + (size_t)r * KTOT + kt + ke);
    }
    __syncthreads();

#pragma unroll
    for (int kk = 0; kk < 2; ++kk) {
      int ko = kk * 32 + ((lane >> 4) << 3);
      bf16x8 a[4], b[4];
#pragma unroll
      for (int m = 0; m < 4; ++m)
        a[m] = *(const bf16x8*)&As[wr + m * 16 + (lane & 15)][ko];
#pragma unroll
      for (int n = 0; n < 4; ++n)
        b[n] = *(const bf16x8*)&Bs[wc + n * 16 + (lane & 15)][ko];
#pragma unroll
      for (int m = 0; m < 4; ++m)
#pragma unroll
        for (int n = 0; n < 4; ++n)
          acc[m][n] = __builtin_amdgcn_mfma_f32_16x16x32_bf16(
              a[m], b[n], acc[m][n], 0, 0, 0);
    }
    __syncthreads();
  }

#pragma unroll
  for (int n = 0; n < 4; ++n) {
    int col = wc + n * 16 + (lane & 15);
    float bb = bias[col];
#pragma unroll
    for (int m = 0; m < 4; ++m) {
      f32x4 v = acc[m][n];
#pragma unroll
      for (int j = 0; j < 4; ++j) {
        int row = row0 + wr + m * 16 + ((lane >> 4) << 2) + j;
        if (row < NN) {
          float o = v[j] + bb;
          if (OUT_BF16) {
            o = fmaxf(o, 0.f);
            ((unsigned short*)Cout)[(size_t)row * DD + col] = f2b(o);
          } else {
            ((float*)Cout)[(size_t)row * DD + col] = o;
          }
        }
      }
    }
  }
}

// ---------------------------------------------------------------------------
extern "C" void kernel_launch(void* const* d_in, const int* in_sizes, int n_in,
                              void* d_out, int out_size, void* d_ws,
                              size_t ws_size, hipStream_t stream) {
  const float* x      = (const float*)d_in[0];
  const int*   eidx   = (const int*)d_in[1];
  const int*   etype  = (const int*)d_in[2];
  const float* basis1 = (const float*)d_in[3];
  const float* comp1  = (const float*)d_in[4];
  const float* root1  = (const float*)d_in[5];
  const float* bias1  = (const float*)d_in[6];
  const float* basis2 = (const float*)d_in[7];
  const float* comp2  = (const float*)d_in[8];
  const float* root2  = (const float*)d_in[9];
  const float* bias2  = (const float*)d_in[10];
  float* out = (float*)d_out;

  const int* src = eidx;
  const int* dst = eidx + NE;

  // workspace layout (16B-aligned chunk sizes)
  unsigned short* Ab  = (unsigned short*)d_ws;         // [MPAD][512] bf16
  unsigned short* xb  = Ab + (size_t)MPAD * KZ;        // [MPAD][128] bf16
  unsigned short* hb  = xb + (size_t)MPAD * DD;        // [MPAD][128] bf16
  unsigned short* BT1 = hb + (size_t)MPAD * DD;        // [128][640] bf16
  unsigned short* BT2 = BT1 + (size_t)DD * KTOT;
  int*  skey = (int*)(BT2 + (size_t)DD * KTOT);        // [NE]
  int*  cnt  = skey + NE;                              // [NR]
  int*  gcur = cnt + NR;                               // [4] (pad)
  int2* od   = (int2*)(gcur + 4);                      // [NN] (offs,deg)
  int*  curs = (int*)(od + NN);                        // [NN]

  const int NB = (NN + 255) / 256;  // 196
  const int EB = (NE + 255) / 256;  // 2344

  hipMemsetAsync(cnt, 0, (size_t)(NR + 4) * sizeof(int), stream);
  prep_kernel<<<PREP_TOTAL, 256, 0, stream>>>(
      x, basis1, root1, basis2, root2, dst, etype, (unsigned*)xb, BT1, BT2,
      cnt);
  offs_kernel<<<NB, 256, 0, stream>>>(cnt, od, curs, gcur);
  sort_kernel<<<EB, 256, 0, stream>>>(src, dst, etype, curs, skey);

  int agg_blocks = NN / 8;        // 6250 (2 nodes per wave, 4 waves/block)
  int gemm_blocks = MPAD / 128;   // 391

  // ---- layer 1 (x -> h, relu, bf16) ----
  agg_kernel<<<agg_blocks, 256, 0, stream>>>((const u32x4*)xb, skey, cnt,
                                             comp1, od, (u32x4*)Ab);
  gemm_mfma<1><<<gemm_blocks, 256, 0, stream>>>(Ab, xb, BT1, bias1, hb);
  // ---- layer 2 (h -> out, f32) ----
  agg_kernel<<<agg_blocks, 256, 0, stream>>>((const u32x4*)hb, skey, cnt,
                                             comp2, od, (u32x4*)Ab);
  gemm_mfma<0><<<gemm_blocks, 256, 0, stream>>>(Ab, hb, BT2, bias2, out);
}